// Round 16
// baseline (128.284 us; speedup 1.0000x reference)
//
#include <hip/hip_runtime.h>
#include <hip/hip_fp16.h>
#include <math.h>

#define N_NODES 2048
#define T_WIN 5
#define D_EMB 64
#define TOPK 21
#define B_BATCH 32
#define BN_TOTAL (B_BATCH * N_NODES)   // 65536
#define EPS_BN 1e-5f
#define NEG_SLOPE 0.2f
#define STATS_STRIDE 16
#define PA_STRIDE 24                   // padded k-stride of paT[i][b][k]

typedef unsigned long long u64;
typedef unsigned short u16;
typedef unsigned int u32;

// ---------------- wave-level helpers (wave = 64 on gfx950) ----------------
__device__ __forceinline__ float wave_sum(float v) {
#pragma unroll
    for (int off = 32; off > 0; off >>= 1) v += __shfl_xor(v, off, 64);
    return v;
}

__device__ __forceinline__ u64 max64(u64 a, u64 b) { return a > b ? a : b; }
__device__ __forceinline__ u64 min64(u64 a, u64 b) { return a < b ? a : b; }

__device__ __forceinline__ u64 bitonic_sort64_desc(u64 key, int lane) {
#pragma unroll
    for (int k = 2; k <= 64; k <<= 1) {
#pragma unroll
        for (int j = k >> 1; j >= 1; j >>= 1) {
            u64 pk = __shfl_xor(key, j, 64);
            bool dirDesc = ((lane & k) == 0);
            bool keepMax = (((lane & j) == 0) == dirDesc);
            key = keepMax ? max64(key, pk) : min64(key, pk);
        }
    }
    return key;
}

__device__ __forceinline__ u64 bitonic_merge_top64(u64 a, u64 b, int lane) {
    u64 br = __shfl(b, 63 - lane, 64);
    u64 c = max64(a, br);
#pragma unroll
    for (int j = 32; j >= 1; j >>= 1) {
        u64 pk = __shfl_xor(c, j, 64);
        bool keepMax = ((lane & j) == 0);
        c = keepMax ? max64(c, pk) : min64(c, pk);
    }
    return c;
}

// bf16 round-to-nearest-even pack/unpack (obufT; measured ~300x worst-case
// amplification through BN 1/sigma + fc — 0.0625 absmax vs 0.224 threshold)
__device__ __forceinline__ u16 f2bf(float f) {
    unsigned u = __float_as_uint(f);
    return (u16)((u + 0x7FFFu + ((u >> 16) & 1u)) >> 16);
}
__device__ __forceinline__ float bf2f(u16 h) {
    return __uint_as_float((unsigned)h << 16);
}

// ---------------- K1: k_preg — fused {raw Gram tiles} + {edge precompute} ---
// [R7: gram writes RAW dots, /(ni*nj) in k_select — bit-identical keys.]
// [R8: grid.sync cross-XCD handoff FAILED; kernel boundaries only fence.]
// [R9: LDS-transpose epilogue had 8-way conflicts — direct mirror writes.]
// [R13/R14: workspace maps re-derived from element counts after overlap bug.]
__global__ __launch_bounds__(256) void k_preg(
    const float* __restrict__ x, const float* __restrict__ W,
    const float* __restrict__ Wb, const float* __restrict__ a_src,
    const float* __restrict__ a_dst, const float* __restrict__ emb,
    float* __restrict__ xs2T, float* __restrict__ xd2T,
    float* __restrict__ es_embP, float* __restrict__ ed_embP,
    float* __restrict__ norms, float* __restrict__ dotM,
    float* __restrict__ stats, float* __restrict__ stats2) {
    __shared__ __align__(16) float As[64][68];   // [d][i] (gram path only)
    __shared__ __align__(16) float Bs[64][68];   // [d][j]
    int t = threadIdx.x;

    if (blockIdx.x >= 528) {
        int eb = blockIdx.x - 528;
        if (eb < 512) {
            // ---- node path: norms + es_emb/ed_emb (wave per node) ----
            if (eb < 2) {
                float* p = eb ? stats2 : stats;
                ((float4*)p)[t] = make_float4(0.f, 0.f, 0.f, 0.f);
            }
            int wid = t >> 6, lane = t & 63;
            int node = eb * 4 + wid;
            float e = emb[node * D_EMB + lane];
            float s2 = wave_sum(e * e);
            float esE = wave_sum(e * a_src[D_EMB + lane]);
            float edE = wave_sum(e * a_dst[D_EMB + lane]);
            if (lane == 0) {
                norms[node] = sqrtf(s2);
                es_embP[node] = esE;
                ed_embP[node] = edE;
            }
        } else {
            // ---- x path: xs/xd = bs + Sum_t x*w ----
            __shared__ float cws[5], cwd[5], cbs[2];
            if (t < 12) {
                int which = (t < 5 || t == 10) ? 0 : 1;
                const float* av = which ? a_dst : a_src;
                const float* sp;
                int stride;
                if (t < 10) { int tt = (t < 5) ? t : t - 5; sp = W + tt; stride = T_WIN; }
                else        { sp = Wb; stride = 1; }
                float acc = 0.f;
                for (int d = 0; d < D_EMB; d++) acc += sp[d * stride] * av[d];
                if (t < 5)       cws[t] = acc;
                else if (t < 10) cwd[t - 5] = acc;
                else             cbs[t - 10] = acc;
            }
            __syncthreads();
            float ws0 = cws[0], ws1 = cws[1], ws2 = cws[2], ws3 = cws[3], ws4 = cws[4];
            float wd0 = cwd[0], wd1 = cwd[1], wd2 = cwd[2], wd3 = cwd[3], wd4 = cwd[4];
            float bss = cbs[0], bsd = cbs[1];
            int base = (eb - 512) * 1024;
#pragma unroll
            for (int r = 0; r < 4; r++) {
                int item = base + 256 * r + t;
                const float* xp = x + (size_t)item * T_WIN;
                float x0 = xp[0], x1 = xp[1], x2 = xp[2], x3 = xp[3], x4 = xp[4];
                xs2T[item] = bss + x0 * ws0 + x1 * ws1 + x2 * ws2 + x3 * ws3 + x4 * ws4;
                xd2T[item] = bsd + x0 * wd0 + x1 * wd1 + x2 * wd2 + x3 * wd3 + x4 * wd4;
            }
        }
        return;
    }

    // ---- gram path: raw Gram tile, symmetric write (dot exactly symmetric)
    int g = blockIdx.x;                          // 0..527
    int a = (int)((sqrtf(8.f * g + 1.f) - 1.f) * 0.5f);
    while ((a + 1) * (a + 2) / 2 <= g) a++;
    while (a * (a + 1) / 2 > g) a--;
    int bq = g - a * (a + 1) / 2;                // 0..a
    int i0 = a * 64, j0 = bq * 64;

    {
        int r = t >> 2, c0 = t & 3;
        const float4* srcA = (const float4*)(emb + (size_t)(i0 + r) * D_EMB);
        const float4* srcB = (const float4*)(emb + (size_t)(j0 + r) * D_EMB);
#pragma unroll
        for (int k = 0; k < 4; k++) {
            int f4 = c0 + 4 * k;
            float4 v = srcA[f4];
            int d = 4 * f4;
            As[d][r] = v.x; As[d + 1][r] = v.y; As[d + 2][r] = v.z; As[d + 3][r] = v.w;
            float4 w = srcB[f4];
            Bs[d][r] = w.x; Bs[d + 1][r] = w.y; Bs[d + 2][r] = w.z; Bs[d + 3][r] = w.w;
        }
    }
    __syncthreads();

    int ti = t & 15, tj = t >> 4;
    float acc[4][4] = {};
#pragma unroll
    for (int d = 0; d < 64; d++) {
        float4 av = *(const float4*)&As[d][4 * ti];
        float4 bv = *(const float4*)&Bs[d][4 * tj];
        acc[0][0] += av.x * bv.x; acc[0][1] += av.x * bv.y; acc[0][2] += av.x * bv.z; acc[0][3] += av.x * bv.w;
        acc[1][0] += av.y * bv.x; acc[1][1] += av.y * bv.y; acc[1][2] += av.y * bv.z; acc[1][3] += av.y * bv.w;
        acc[2][0] += av.z * bv.x; acc[2][1] += av.z * bv.y; acc[2][2] += av.z * bv.z; acc[2][3] += av.z * bv.w;
        acc[3][0] += av.w * bv.x; acc[3][1] += av.w * bv.y; acc[3][2] += av.w * bv.z; acc[3][3] += av.w * bv.w;
    }

#pragma unroll
    for (int r = 0; r < 4; r++) {
        float4 o;
        o.x = acc[r][0]; o.y = acc[r][1]; o.z = acc[r][2]; o.w = acc[r][3];
        int i = i0 + 4 * ti + r;
        *(float4*)(dotM + (size_t)i * N_NODES + j0 + 4 * tj) = o;
        dotM[(size_t)(j0 + 4 * tj + 0) * N_NODES + i] = o.x;
        dotM[(size_t)(j0 + 4 * tj + 1) * N_NODES + i] = o.y;
        dotM[(size_t)(j0 + 4 * tj + 2) * N_NODES + i] = o.z;
        dotM[(size_t)(j0 + 4 * tj + 3) * N_NODES + i] = o.w;
    }
}

// ---------------- K2: k_selal — top-21 + fused alpha -> paT[i][b][k] --------
// [R5/R7 scan: wave-pair per row, 2-way split (R9: flush count dominates).]
// NEW (r16): k_alpha's work moves into this block's epilogue. The merged
// top-21 of each row is broadcast via LDS; then all 256 threads compute
// alpha for (2 rows x 32 b): 4 lanes per (row,b), 5-6 k's each, quad-shfl
// max (exact) + sum (reassoc ~1e-7, buried under f16 alpha rounding).
// paT layout [i][b][24]: 96 B aligned segment per (i,b) -> k_msg loads 21
// records in 6 wide loads instead of 21 dwords. idxT buffer eliminated.
__global__ __launch_bounds__(256) void k_selal(
    const float* __restrict__ dotM, const float* __restrict__ norms,
    const float* __restrict__ xs2T, const float* __restrict__ xd2T,
    const float* __restrict__ es_embP, const float* __restrict__ ed_embP,
    u32* __restrict__ paT) {
    __shared__ u64 candbuf[4][128];
    __shared__ u64 mbuf[2][64];
    __shared__ int sjk[2][PA_STRIDE];
    int tid = threadIdx.x;
    int wid = tid >> 6, lane = tid & 63;
    int pair = wid >> 1;                 // row within block (0..1)
    int half = wid & 1;                  // 0: j<1024, 1: j>=1024
    int i = blockIdx.x * 2 + pair;
    int jbase = half * (N_NODES / 2);
    const float* row = dotM + (size_t)i * N_NODES + jbase;
    u64* buf = candbuf[wid];
    float ni = norms[i];

    u64 a = 0;
    u64 t = 0;
    int cnt = 0;
    float vcur = row[lane];
    float ncur = norms[jbase + lane];

#pragma unroll 1
    for (int c = 0; c < N_NODES / 128; c++) {   // 16 chunks of 64
        int j = c * 64 + lane;
        float dv = vcur, nv = ncur;
        if (c < N_NODES / 128 - 1) {
            vcur = row[j + 64];
            ncur = norms[jbase + j + 64];
        }
        float v = dv / (ni * nv);
        unsigned u = __float_as_uint(v);
        u = (u & 0x80000000u) ? ~u : (u | 0x80000000u);
        u64 key = ((u64)u << 32) | (unsigned)(~(j + jbase));
        unsigned long long ball = __ballot(key > t);
        if (ball) {
            int ofs = __popcll(ball & ((1ull << lane) - 1ull));
            if (key > t) buf[cnt + ofs] = key;
            cnt += (int)__popcll(ball);
            if (cnt >= 64) {
                u64 nk = buf[lane];
                nk = bitonic_sort64_desc(nk, lane);
                a = bitonic_merge_top64(a, nk, lane);
                t = __shfl(a, 20, 64);
                int rem = cnt - 64;
                u64 mv = (lane < rem) ? buf[64 + lane] : 0;
                if (lane < rem) buf[lane] = mv;
                cnt = rem;
            }
        }
    }
    while (cnt > 0) {
        int take = cnt < 64 ? cnt : 64;
        u64 nk = (lane < take) ? buf[lane] : 0;
        nk = bitonic_sort64_desc(nk, lane);
        a = bitonic_merge_top64(a, nk, lane);
        t = __shfl(a, 20, 64);
        int rem = cnt - take;
        u64 mv = (lane < rem) ? buf[take + lane] : 0;
        if (lane < rem) buf[lane] = mv;
        cnt = rem;
    }

    // pair merge: upper wave publishes its sorted top-64; lower wave merges
    if (half) mbuf[pair][lane] = a;
    __syncthreads();
    if (!half) {
        u64 bv = mbuf[pair][lane];
        a = bitonic_merge_top64(a, bv, lane);
        if (lane < TOPK) sjk[pair][lane] = (int)(~(unsigned)a);
    }
    __syncthreads();

    // ---- fused alpha epilogue: 64 (row,b) pairs, 4 lanes each ----
    {
        int p = wid * 16 + (lane >> 2);      // 0..63
        int prow = p >> 5;                   // 0..1
        int bb = p & 31;
        int sub = lane & 3;
        int irow = blockIdx.x * 2 + prow;
        float es = xs2T[(size_t)bb * N_NODES + irow] + es_embP[irow];
        float ev[6];
        int jv[6];
        float m = -3e38f;
#pragma unroll
        for (int q = 0; q < 6; q++) {
            int k = sub + 4 * q;
            bool ok = k < TOPK;
            int kk = ok ? k : 0;
            int jkv = sjk[prow][kk];
            float e = es + (xd2T[(size_t)bb * N_NODES + jkv] + ed_embP[jkv]);
            e = e > 0.f ? e : NEG_SLOPE * e;
            e = ok ? e : -3e38f;
            ev[q] = e;
            jv[q] = jkv;
            m = fmaxf(m, e);
        }
        m = fmaxf(m, __shfl_xor(m, 1, 64));  // quad-reduce (groups aligned)
        m = fmaxf(m, __shfl_xor(m, 2, 64));
        float s = 0.f;
#pragma unroll
        for (int q = 0; q < 6; q++) {
            ev[q] = __expf(ev[q] - m);
            s += ev[q];
        }
        s += __shfl_xor(s, 1, 64);
        s += __shfl_xor(s, 2, 64);
        float inv = 1.0f / s;
        u32* seg = paT + ((size_t)irow * B_BATCH + bb) * PA_STRIDE;
#pragma unroll
        for (int q = 0; q < 6; q++) {
            int k = sub + 4 * q;
            if (k < TOPK) {
                u16 ah = __half_as_ushort(__float2half_rn(ev[q] * inv));
                seg[k] = ((u32)jv[q] << 16) | (u32)ah;
            }
        }
    }
}

// ---------------- K3: message passing — f16 h-tile, segment pa, hfma2 -------
// [R15: hts[2048][8] f16, one ds_read_b128 covers 8 dims; __hfma2 gather.]
// [R16: paT[i][b][24] segment -> 21 records in 6 wide loads (5x dwordx4 +
//  1 dword) per item instead of 21 scalar dword loads. Same L2 bytes.]
__global__ __launch_bounds__(256, 4) void k_msg(
    const float* __restrict__ x, const float* __restrict__ W,
    const float* __restrict__ Wb, const u32* __restrict__ paT,
    const float* __restrict__ emb, uint4* __restrict__ obufT,
    float* __restrict__ stats, float* __restrict__ stats2) {
    __shared__ __align__(16) u32 hts[N_NODES][4];   // 32 KB, 8 f16/row
    __shared__ float sred[2][4][8];

    int g = blockIdx.x;                        // 512 = 32 b x 8 cc x 2 half
    int b = g & 31;
    int cc = (g >> 5) & 7;
    int half = g >> 8;
    int d0 = cc * 8;
    int ibase = half * (N_NODES / 2);
    int t = threadIdx.x;
    int wid = t >> 6, lane = t & 63;

    // ---- build f16 h-tile from x (full 2048 rows) ----
    float wc[8][T_WIN], wb8[8];
#pragma unroll
    for (int q = 0; q < 8; q++) {
        wb8[q] = Wb[d0 + q];
#pragma unroll
        for (int tt = 0; tt < T_WIN; tt++) wc[q][tt] = W[(d0 + q) * T_WIN + tt];
    }
    const float* xb = x + (size_t)b * N_NODES * T_WIN;
#pragma unroll
    for (int r = 0; r < 8; r++) {
        int row = t + 256 * r;
        const float* xr = xb + row * T_WIN;
        float x0 = xr[0], x1 = xr[1], x2 = xr[2], x3 = xr[3], x4 = xr[4];
        float h[8];
#pragma unroll
        for (int q = 0; q < 8; q++)
            h[q] = wb8[q] + x0 * wc[q][0] + x1 * wc[q][1] + x2 * wc[q][2]
                 + x3 * wc[q][3] + x4 * wc[q][4];
        __half2 p0 = __floats2half2_rn(h[0], h[1]);
        __half2 p1 = __floats2half2_rn(h[2], h[3]);
        __half2 p2 = __floats2half2_rn(h[4], h[5]);
        __half2 p3 = __floats2half2_rn(h[6], h[7]);
        uint4 sv;
        sv.x = *(u32*)&p0; sv.y = *(u32*)&p1; sv.z = *(u32*)&p2; sv.w = *(u32*)&p3;
        *(uint4*)&hts[row][0] = sv;
    }
    __syncthreads();

    // ---- gather: 1024 items (this half), 4 per thread ----
    float sacc[8] = {}, sacc2[8] = {};
#pragma unroll 1
    for (int r = 0; r < 4; r++) {
        int i = ibase + 256 * r + t;
        const u32* seg = paT + ((size_t)i * B_BATCH + b) * PA_STRIDE;
        const uint4* seg4 = (const uint4*)seg;       // 96 B, 16B-aligned
        uint4 va = seg4[0], vb = seg4[1], vc4 = seg4[2], vd = seg4[3], ve = seg4[4];
        u32 p20 = seg[20];
        u32 pk[21];
        pk[0] = va.x;  pk[1] = va.y;  pk[2] = va.z;  pk[3] = va.w;
        pk[4] = vb.x;  pk[5] = vb.y;  pk[6] = vb.z;  pk[7] = vb.w;
        pk[8] = vc4.x; pk[9] = vc4.y; pk[10] = vc4.z; pk[11] = vc4.w;
        pk[12] = vd.x; pk[13] = vd.y; pk[14] = vd.z; pk[15] = vd.w;
        pk[16] = ve.x; pk[17] = ve.y; pk[18] = ve.z; pk[19] = ve.w;
        pk[20] = p20;

        __half2 z01 = __floats2half2_rn(0.f, 0.f);
        __half2 z23 = z01, z45 = z01, z67 = z01;
#pragma unroll
        for (int k = 0; k < TOPK; k++) {
            u32 pa = pk[k];
            int jk = (int)(pa >> 16);
            __half2 av = __half2half2(__ushort_as_half((u16)(pa & 0xFFFFu)));
            uint4 hv = *(const uint4*)&hts[jk][0];   // one ds_read_b128, 8 dims
            z01 = __hfma2(av, *(__half2*)&hv.x, z01);
            z23 = __hfma2(av, *(__half2*)&hv.y, z23);
            z45 = __hfma2(av, *(__half2*)&hv.z, z45);
            z67 = __hfma2(av, *(__half2*)&hv.w, z67);
        }
        float2 f01 = __half22float2(z01);
        float2 f23 = __half22float2(z23);
        float2 f45 = __half22float2(z45);
        float2 f67 = __half22float2(z67);
        float4 e0 = *(const float4*)(emb + (size_t)i * D_EMB + d0);
        float4 e1 = *(const float4*)(emb + (size_t)i * D_EMB + d0 + 4);
        float o[8];
        o[0] = fmaxf(f01.x, 0.f) * e0.x;
        o[1] = fmaxf(f01.y, 0.f) * e0.y;
        o[2] = fmaxf(f23.x, 0.f) * e0.z;
        o[3] = fmaxf(f23.y, 0.f) * e0.w;
        o[4] = fmaxf(f45.x, 0.f) * e1.x;
        o[5] = fmaxf(f45.y, 0.f) * e1.y;
        o[6] = fmaxf(f67.x, 0.f) * e1.z;
        o[7] = fmaxf(f67.y, 0.f) * e1.w;
        uint4 st;
        st.x = (u32)f2bf(o[0]) | ((u32)f2bf(o[1]) << 16);
        st.y = (u32)f2bf(o[2]) | ((u32)f2bf(o[3]) << 16);
        st.z = (u32)f2bf(o[4]) | ((u32)f2bf(o[5]) << 16);
        st.w = (u32)f2bf(o[6]) | ((u32)f2bf(o[7]) << 16);
        obufT[((size_t)cc * B_BATCH + b) * N_NODES + i] = st;
#pragma unroll
        for (int q = 0; q < 8; q++) {
            sacc[q] += o[q];
            sacc2[q] += o[q] * o[q];
        }
    }

    // ---- stats partials (both halves atomically add to the same slots) ----
#pragma unroll
    for (int q = 0; q < 8; q++) {
        sacc[q] = wave_sum(sacc[q]);
        sacc2[q] = wave_sum(sacc2[q]);
    }
    if (lane == 0) {
#pragma unroll
        for (int q = 0; q < 8; q++) {
            sred[0][wid][q] = sacc[q];
            sred[1][wid][q] = sacc2[q];
        }
    }
    __syncthreads();
    if (t < 16) {
        int q = t & 7, which = t >> 3;
        float v = sred[which][0][q] + sred[which][1][q] + sred[which][2][q] + sred[which][3][q];
        float* dst = which ? stats2 : stats;
        atomicAdd(&dst[(d0 + q) * STATS_STRIDE], v);
    }
}

// ---------------- K4: BN apply + relu + fc — bf16x8 c-panel sweep -----------
__global__ __launch_bounds__(256) void k_out(
    const uint4* __restrict__ obufT, const float* __restrict__ stats,
    const float* __restrict__ stats2, const float* __restrict__ gamma,
    const float* __restrict__ beta, const float* __restrict__ fc_w,
    const float* __restrict__ fc_b, float* __restrict__ out) {
    __shared__ float smean[64], sinv[64], sg[64], sb[64], sf[64];
    int t = threadIdx.x;
    int g = blockIdx.x;                 // 256 = 32 b x 8 n-chunks
    int b = g & 31, nc = g >> 5;
    int n = nc * 256 + t;
    const float invM = 1.0f / (float)BN_TOTAL;

    if (t < 64) {
        float mn = stats[t * STATS_STRIDE] * invM;
        float var = stats2[t * STATS_STRIDE] * invM - mn * mn;
        smean[t] = mn;
        sinv[t] = rsqrtf(var + EPS_BN);
        sg[t] = gamma[t]; sb[t] = beta[t]; sf[t] = fc_w[t];
    }
    __syncthreads();

    float fb = fc_b[0];
    float p = 0.f;
#pragma unroll
    for (int cc = 0; cc < 8; cc++) {
        uint4 hv = obufT[((size_t)cc * B_BATCH + b) * N_NODES + n];
        int d = cc * 8;
        float o[8];
        o[0] = bf2f((u16)(hv.x & 0xFFFFu)); o[1] = bf2f((u16)(hv.x >> 16));
        o[2] = bf2f((u16)(hv.y & 0xFFFFu)); o[3] = bf2f((u16)(hv.y >> 16));
        o[4] = bf2f((u16)(hv.z & 0xFFFFu)); o[5] = bf2f((u16)(hv.z >> 16));
        o[6] = bf2f((u16)(hv.w & 0xFFFFu)); o[7] = bf2f((u16)(hv.w >> 16));
#pragma unroll
        for (int q = 0; q < 8; q++) {
            float v = fmaxf((o[q] - smean[d + q]) * sinv[d + q] * sg[d + q] + sb[d + q], 0.f);
            p = fmaf(v, sf[d + q], p);
        }
    }
    out[b * N_NODES + n] = p + fb;
}

// ---------------- launch ----------------------------------------------------
extern "C" void kernel_launch(void* const* d_in, const int* in_sizes, int n_in,
                              void* d_out, int out_size, void* d_ws, size_t ws_size,
                              hipStream_t stream) {
    const float* x     = (const float*)d_in[0];
    const float* emb   = (const float*)d_in[1];
    const float* W     = (const float*)d_in[2];
    const float* Wb    = (const float*)d_in[3];
    const float* a_src = (const float*)d_in[4];
    const float* a_dst = (const float*)d_in[5];
    const float* gamma = (const float*)d_in[6];
    const float* beta  = (const float*)d_in[7];
    const float* fc_w  = (const float*)d_in[8];
    const float* fc_b  = (const float*)d_in[9];
    float* out = (float*)d_out;

    // Workspace map (re-derived from ELEMENT COUNTS; idxT eliminated):
    //   stats    [0,        4096)
    //   stats2   [4096,     8192)
    //   norms    [8192,     16384)    2048*4          = 8,192
    //   es_embP  [16384,    24576)    2048*4          = 8,192
    //   ed_embP  [24576,    32768)    2048*4          = 8,192
    //   xs2T     [32768,    294912)   65536*4         = 262,144
    //   xd2T     [294912,   557056)   65536*4         = 262,144
    //   paT      [557056,   6848512)  2048*32*24*4    = 6,291,456
    //   dotM     [6848512,  23625728) 2048*2048*4     = 16,777,216
    //   obufT  = dotM alias (8.4 MB bf16x8; dotM dead after k_selal)
    char* ws = (char*)d_ws;
    float* stats   = (float*)(ws + 0);
    float* stats2  = (float*)(ws + 4096);
    float* norms   = (float*)(ws + 8192);
    float* es_embP = (float*)(ws + 16384);
    float* ed_embP = (float*)(ws + 24576);
    float* xs2T    = (float*)(ws + 32768);
    float* xd2T    = (float*)(ws + 294912);
    u32*   paT     = (u32*)  (ws + 557056);
    float* dotM    = (float*)(ws + 6848512);
    uint4* obufT   = (uint4*)dotM;
    // total: 23,625,728 bytes

    k_preg<<<1104, 256, 0, stream>>>(x, W, Wb, a_src, a_dst, emb,
                                     xs2T, xd2T, es_embP, ed_embP, norms,
                                     dotM, stats, stats2);
    k_selal<<<N_NODES / 2, 256, 0, stream>>>(dotM, norms, xs2T, xd2T,
                                             es_embP, ed_embP, paT);
    k_msg<<<512, 256, 0, stream>>>(x, W, Wb, paT, emb, obufT, stats, stats2);
    k_out<<<256, 256, 0, stream>>>(obufT, stats, stats2, gamma, beta, fc_w, fc_b, out);
}

// Round 17
// 126.443 us; speedup vs baseline: 1.0146x; 1.0146x over previous
//
#include <hip/hip_runtime.h>
#include <hip/hip_fp16.h>
#include <math.h>

#define N_NODES 2048
#define T_WIN 5
#define D_EMB 64
#define TOPK 21
#define B_BATCH 32
#define BN_TOTAL (B_BATCH * N_NODES)   // 65536
#define EPS_BN 1e-5f
#define NEG_SLOPE 0.2f
#define STATS_STRIDE 16

typedef unsigned long long u64;
typedef unsigned short u16;
typedef unsigned int u32;

// ---------------- wave-level helpers (wave = 64 on gfx950) ----------------
__device__ __forceinline__ float wave_sum(float v) {
#pragma unroll
    for (int off = 32; off > 0; off >>= 1) v += __shfl_xor(v, off, 64);
    return v;
}

__device__ __forceinline__ u64 max64(u64 a, u64 b) { return a > b ? a : b; }
__device__ __forceinline__ u64 min64(u64 a, u64 b) { return a < b ? a : b; }

__device__ __forceinline__ u64 bitonic_sort64_desc(u64 key, int lane) {
#pragma unroll
    for (int k = 2; k <= 64; k <<= 1) {
#pragma unroll
        for (int j = k >> 1; j >= 1; j >>= 1) {
            u64 pk = __shfl_xor(key, j, 64);
            bool dirDesc = ((lane & k) == 0);
            bool keepMax = (((lane & j) == 0) == dirDesc);
            key = keepMax ? max64(key, pk) : min64(key, pk);
        }
    }
    return key;
}

__device__ __forceinline__ u64 bitonic_merge_top64(u64 a, u64 b, int lane) {
    u64 br = __shfl(b, 63 - lane, 64);
    u64 c = max64(a, br);
#pragma unroll
    for (int j = 32; j >= 1; j >>= 1) {
        u64 pk = __shfl_xor(c, j, 64);
        bool keepMax = ((lane & j) == 0);
        c = keepMax ? max64(c, pk) : min64(c, pk);
    }
    return c;
}

// bf16 round-to-nearest-even pack/unpack (obufT; measured ~300x worst-case
// amplification through BN 1/sigma + fc — 0.0625 absmax vs 0.224 threshold)
__device__ __forceinline__ u16 f2bf(float f) {
    unsigned u = __float_as_uint(f);
    return (u16)((u + 0x7FFFu + ((u >> 16) & 1u)) >> 16);
}
__device__ __forceinline__ float bf2f(u16 h) {
    return __uint_as_float((unsigned)h << 16);
}

// ---------------- K1: k_preg — fused {raw Gram tiles} + {edge precompute} ---
// [R7: gram writes RAW dots, /(ni*nj) in k_select — bit-identical keys.]
// [R8: grid.sync cross-XCD handoff FAILED; kernel boundaries only fence.]
// [R9: LDS-transpose epilogue had 8-way conflicts — direct mirror writes.]
// [R13/R14: workspace maps re-derived from element counts after overlap bug.]
// [R16 post-mortem: k_alpha fusion + [i][b][24] paT layout broke coalescing
//  (adjacent lanes 3 KB apart in k_msg) — reverted to R15 structure.]
__global__ __launch_bounds__(256) void k_preg(
    const float* __restrict__ x, const float* __restrict__ W,
    const float* __restrict__ Wb, const float* __restrict__ a_src,
    const float* __restrict__ a_dst, const float* __restrict__ emb,
    float* __restrict__ xs2T, float* __restrict__ xd2T,
    float* __restrict__ es_embP, float* __restrict__ ed_embP,
    float* __restrict__ norms, float* __restrict__ dotM,
    float* __restrict__ stats, float* __restrict__ stats2) {
    __shared__ __align__(16) float As[64][68];   // [d][i] (gram path only)
    __shared__ __align__(16) float Bs[64][68];   // [d][j]
    int t = threadIdx.x;

    if (blockIdx.x >= 528) {
        int eb = blockIdx.x - 528;
        if (eb < 512) {
            // ---- node path: norms + es_emb/ed_emb (wave per node) ----
            if (eb < 2) {
                float* p = eb ? stats2 : stats;
                ((float4*)p)[t] = make_float4(0.f, 0.f, 0.f, 0.f);
            }
            int wid = t >> 6, lane = t & 63;
            int node = eb * 4 + wid;
            float e = emb[node * D_EMB + lane];
            float s2 = wave_sum(e * e);
            float esE = wave_sum(e * a_src[D_EMB + lane]);
            float edE = wave_sum(e * a_dst[D_EMB + lane]);
            if (lane == 0) {
                norms[node] = sqrtf(s2);
                es_embP[node] = esE;
                ed_embP[node] = edE;
            }
        } else {
            // ---- x path: xs/xd = bs + Sum_t x*w ----
            __shared__ float cws[5], cwd[5], cbs[2];
            if (t < 12) {
                int which = (t < 5 || t == 10) ? 0 : 1;
                const float* av = which ? a_dst : a_src;
                const float* sp;
                int stride;
                if (t < 10) { int tt = (t < 5) ? t : t - 5; sp = W + tt; stride = T_WIN; }
                else        { sp = Wb; stride = 1; }
                float acc = 0.f;
                for (int d = 0; d < D_EMB; d++) acc += sp[d * stride] * av[d];
                if (t < 5)       cws[t] = acc;
                else if (t < 10) cwd[t - 5] = acc;
                else             cbs[t - 10] = acc;
            }
            __syncthreads();
            float ws0 = cws[0], ws1 = cws[1], ws2 = cws[2], ws3 = cws[3], ws4 = cws[4];
            float wd0 = cwd[0], wd1 = cwd[1], wd2 = cwd[2], wd3 = cwd[3], wd4 = cwd[4];
            float bss = cbs[0], bsd = cbs[1];
            int base = (eb - 512) * 1024;
#pragma unroll
            for (int r = 0; r < 4; r++) {
                int item = base + 256 * r + t;
                const float* xp = x + (size_t)item * T_WIN;
                float x0 = xp[0], x1 = xp[1], x2 = xp[2], x3 = xp[3], x4 = xp[4];
                xs2T[item] = bss + x0 * ws0 + x1 * ws1 + x2 * ws2 + x3 * ws3 + x4 * ws4;
                xd2T[item] = bsd + x0 * wd0 + x1 * wd1 + x2 * wd2 + x3 * wd3 + x4 * wd4;
            }
        }
        return;
    }

    // ---- gram path: raw Gram tile, symmetric write (dot exactly symmetric)
    int g = blockIdx.x;                          // 0..527
    int a = (int)((sqrtf(8.f * g + 1.f) - 1.f) * 0.5f);
    while ((a + 1) * (a + 2) / 2 <= g) a++;
    while (a * (a + 1) / 2 > g) a--;
    int bq = g - a * (a + 1) / 2;                // 0..a
    int i0 = a * 64, j0 = bq * 64;

    {
        int r = t >> 2, c0 = t & 3;
        const float4* srcA = (const float4*)(emb + (size_t)(i0 + r) * D_EMB);
        const float4* srcB = (const float4*)(emb + (size_t)(j0 + r) * D_EMB);
#pragma unroll
        for (int k = 0; k < 4; k++) {
            int f4 = c0 + 4 * k;
            float4 v = srcA[f4];
            int d = 4 * f4;
            As[d][r] = v.x; As[d + 1][r] = v.y; As[d + 2][r] = v.z; As[d + 3][r] = v.w;
            float4 w = srcB[f4];
            Bs[d][r] = w.x; Bs[d + 1][r] = w.y; Bs[d + 2][r] = w.z; Bs[d + 3][r] = w.w;
        }
    }
    __syncthreads();

    int ti = t & 15, tj = t >> 4;
    float acc[4][4] = {};
#pragma unroll
    for (int d = 0; d < 64; d++) {
        float4 av = *(const float4*)&As[d][4 * ti];
        float4 bv = *(const float4*)&Bs[d][4 * tj];
        acc[0][0] += av.x * bv.x; acc[0][1] += av.x * bv.y; acc[0][2] += av.x * bv.z; acc[0][3] += av.x * bv.w;
        acc[1][0] += av.y * bv.x; acc[1][1] += av.y * bv.y; acc[1][2] += av.y * bv.z; acc[1][3] += av.y * bv.w;
        acc[2][0] += av.z * bv.x; acc[2][1] += av.z * bv.y; acc[2][2] += av.z * bv.z; acc[2][3] += av.z * bv.w;
        acc[3][0] += av.w * bv.x; acc[3][1] += av.w * bv.y; acc[3][2] += av.w * bv.z; acc[3][3] += av.w * bv.w;
    }

#pragma unroll
    for (int r = 0; r < 4; r++) {
        float4 o;
        o.x = acc[r][0]; o.y = acc[r][1]; o.z = acc[r][2]; o.w = acc[r][3];
        int i = i0 + 4 * ti + r;
        *(float4*)(dotM + (size_t)i * N_NODES + j0 + 4 * tj) = o;
        dotM[(size_t)(j0 + 4 * tj + 0) * N_NODES + i] = o.x;
        dotM[(size_t)(j0 + 4 * tj + 1) * N_NODES + i] = o.y;
        dotM[(size_t)(j0 + 4 * tj + 2) * N_NODES + i] = o.z;
        dotM[(size_t)(j0 + 4 * tj + 3) * N_NODES + i] = o.w;
    }
}

// ---------------- K2: top-21 selection — wave-pair split, on-the-fly norm ---
// [R5/R7 form; R9: 2-way split is the sweet spot (flush count dominates).]
__global__ __launch_bounds__(256) void k_select(
    const float* __restrict__ dotM, const float* __restrict__ norms,
    int* __restrict__ idxT) {
    __shared__ u64 candbuf[4][128];
    __shared__ u64 mbuf[2][64];
    int tid = threadIdx.x;
    int wid = tid >> 6, lane = tid & 63;
    int pair = wid >> 1;                 // row within block (0..1)
    int half = wid & 1;                  // 0: j<1024, 1: j>=1024
    int i = blockIdx.x * 2 + pair;
    int jbase = half * (N_NODES / 2);
    const float* row = dotM + (size_t)i * N_NODES + jbase;
    u64* buf = candbuf[wid];
    float ni = norms[i];

    u64 a = 0;
    u64 t = 0;
    int cnt = 0;
    float vcur = row[lane];
    float ncur = norms[jbase + lane];

#pragma unroll 1
    for (int c = 0; c < N_NODES / 128; c++) {   // 16 chunks of 64
        int j = c * 64 + lane;
        float dv = vcur, nv = ncur;
        if (c < N_NODES / 128 - 1) {
            vcur = row[j + 64];
            ncur = norms[jbase + j + 64];
        }
        float v = dv / (ni * nv);
        unsigned u = __float_as_uint(v);
        u = (u & 0x80000000u) ? ~u : (u | 0x80000000u);
        u64 key = ((u64)u << 32) | (unsigned)(~(j + jbase));
        unsigned long long ball = __ballot(key > t);
        if (ball) {
            int ofs = __popcll(ball & ((1ull << lane) - 1ull));
            if (key > t) buf[cnt + ofs] = key;
            cnt += (int)__popcll(ball);
            if (cnt >= 64) {
                u64 nk = buf[lane];
                nk = bitonic_sort64_desc(nk, lane);
                a = bitonic_merge_top64(a, nk, lane);
                t = __shfl(a, 20, 64);
                int rem = cnt - 64;
                u64 mv = (lane < rem) ? buf[64 + lane] : 0;
                if (lane < rem) buf[lane] = mv;
                cnt = rem;
            }
        }
    }
    while (cnt > 0) {
        int take = cnt < 64 ? cnt : 64;
        u64 nk = (lane < take) ? buf[lane] : 0;
        nk = bitonic_sort64_desc(nk, lane);
        a = bitonic_merge_top64(a, nk, lane);
        t = __shfl(a, 20, 64);
        int rem = cnt - take;
        u64 mv = (lane < rem) ? buf[take + lane] : 0;
        if (lane < rem) buf[lane] = mv;
        cnt = rem;
    }

    // pair merge: upper wave publishes its sorted top-64; lower wave merges
    if (half) mbuf[pair][lane] = a;
    __syncthreads();
    if (!half) {
        u64 bv = mbuf[pair][lane];
        a = bitonic_merge_top64(a, bv, lane);
        if (lane < TOPK) idxT[lane * N_NODES + i] = (int)(~(unsigned)a);
    }
}

// ---------------- K3: k_alpha — softmax -> packed paT[b][k][i]={idx,a-f16} --
// [R14 verified: paT u32 = (jk<<16)|f16(alpha), one dword/neighbor in k_msg.
//  R16 lesson: this LDS-staged structure + coalesced [b][k][i] layout beats
//  the "fewer instructions" fused/segment variant — keep it.]
__global__ __launch_bounds__(256) void k_alpha(
    const int* __restrict__ idxT, const float* __restrict__ xs2T,
    const float* __restrict__ xd2T, const float* __restrict__ es_embP,
    const float* __restrict__ ed_embP, u32* __restrict__ paT) {
    __shared__ float sed[N_NODES];   // 8 KB
    int g = blockIdx.x;
    int b = g & 31;
    int i0 = (g >> 5) * 256;
    int t = threadIdx.x;

    {
        const float4* sxd = (const float4*)(xd2T + (size_t)b * N_NODES);
        const float4* sde = (const float4*)(ed_embP);
        float4* dst = (float4*)sed;
#pragma unroll
        for (int q = 0; q < 2; q++) {
            int idx = t + 256 * q;
            float4 u = sxd[idx];
            float4 v = sde[idx];
            dst[idx] = make_float4(u.x + v.x, u.y + v.y, u.z + v.z, u.w + v.w);
        }
    }
    __syncthreads();

    int i = i0 + t;
    float es = xs2T[(size_t)b * N_NODES + i] + es_embP[i];
    int jk[TOPK];
    float ev[TOPK];
    float m = -3e38f;
#pragma unroll
    for (int k = 0; k < TOPK; k++) {
        jk[k] = idxT[k * N_NODES + i];
        float e = es + sed[jk[k]];
        e = e > 0.f ? e : NEG_SLOPE * e;
        ev[k] = e;
        m = fmaxf(m, e);
    }
    float s = 0.f;
#pragma unroll
    for (int k = 0; k < TOPK; k++) {
        ev[k] = __expf(ev[k] - m);
        s += ev[k];
    }
    float inv = 1.0f / s;
#pragma unroll
    for (int k = 0; k < TOPK; k++) {
        u16 ah = __half_as_ushort(__float2half_rn(ev[k] * inv));
        paT[((size_t)b * TOPK + k) * N_NODES + i] = ((u32)jk[k] << 16) | (u32)ah;
    }
}

// ---------------- K4: message passing — f16 h-tile, packed pa, hfma2 --------
// [R15 verified: hts[2048][8] f16 (32 KB), one ds_read_b128 covers 8 dims;
//  __hfma2 gather; paT dword loads coalesced in i. 4 blocks/CU.]
__global__ __launch_bounds__(256, 4) void k_msg(
    const float* __restrict__ x, const float* __restrict__ W,
    const float* __restrict__ Wb, const u32* __restrict__ paT,
    const float* __restrict__ emb, uint4* __restrict__ obufT,
    float* __restrict__ stats, float* __restrict__ stats2) {
    __shared__ __align__(16) u32 hts[N_NODES][4];   // 32 KB, 8 f16/row
    __shared__ float sred[2][4][8];

    int g = blockIdx.x;                        // 512 = 32 b x 8 cc x 2 half
    int b = g & 31;
    int cc = (g >> 5) & 7;
    int half = g >> 8;
    int d0 = cc * 8;
    int ibase = half * (N_NODES / 2);
    int t = threadIdx.x;
    int wid = t >> 6, lane = t & 63;

    // ---- build f16 h-tile from x (full 2048 rows) ----
    float wc[8][T_WIN], wb8[8];
#pragma unroll
    for (int q = 0; q < 8; q++) {
        wb8[q] = Wb[d0 + q];
#pragma unroll
        for (int tt = 0; tt < T_WIN; tt++) wc[q][tt] = W[(d0 + q) * T_WIN + tt];
    }
    const float* xb = x + (size_t)b * N_NODES * T_WIN;
#pragma unroll
    for (int r = 0; r < 8; r++) {
        int row = t + 256 * r;
        const float* xr = xb + row * T_WIN;
        float x0 = xr[0], x1 = xr[1], x2 = xr[2], x3 = xr[3], x4 = xr[4];
        float h[8];
#pragma unroll
        for (int q = 0; q < 8; q++)
            h[q] = wb8[q] + x0 * wc[q][0] + x1 * wc[q][1] + x2 * wc[q][2]
                 + x3 * wc[q][3] + x4 * wc[q][4];
        __half2 p0 = __floats2half2_rn(h[0], h[1]);
        __half2 p1 = __floats2half2_rn(h[2], h[3]);
        __half2 p2 = __floats2half2_rn(h[4], h[5]);
        __half2 p3 = __floats2half2_rn(h[6], h[7]);
        uint4 sv;
        sv.x = *(u32*)&p0; sv.y = *(u32*)&p1; sv.z = *(u32*)&p2; sv.w = *(u32*)&p3;
        *(uint4*)&hts[row][0] = sv;
    }
    __syncthreads();

    // ---- gather: 1024 items (this half), 4 per thread ----
    float sacc[8] = {}, sacc2[8] = {};
    const u32* pb = paT + (size_t)b * TOPK * N_NODES;
#pragma unroll 1
    for (int r = 0; r < 4; r++) {
        int i = ibase + 256 * r + t;
        __half2 z01 = __floats2half2_rn(0.f, 0.f);
        __half2 z23 = z01, z45 = z01, z67 = z01;
#pragma unroll
        for (int k = 0; k < TOPK; k++) {
            u32 pa = pb[(size_t)k * N_NODES + i];    // coalesced, 1 dword
            int jk = (int)(pa >> 16);
            __half2 av = __half2half2(__ushort_as_half((u16)(pa & 0xFFFFu)));
            uint4 hv = *(const uint4*)&hts[jk][0];   // one ds_read_b128, 8 dims
            z01 = __hfma2(av, *(__half2*)&hv.x, z01);
            z23 = __hfma2(av, *(__half2*)&hv.y, z23);
            z45 = __hfma2(av, *(__half2*)&hv.z, z45);
            z67 = __hfma2(av, *(__half2*)&hv.w, z67);
        }
        float2 f01 = __half22float2(z01);
        float2 f23 = __half22float2(z23);
        float2 f45 = __half22float2(z45);
        float2 f67 = __half22float2(z67);
        float4 e0 = *(const float4*)(emb + (size_t)i * D_EMB + d0);
        float4 e1 = *(const float4*)(emb + (size_t)i * D_EMB + d0 + 4);
        float o[8];
        o[0] = fmaxf(f01.x, 0.f) * e0.x;
        o[1] = fmaxf(f01.y, 0.f) * e0.y;
        o[2] = fmaxf(f23.x, 0.f) * e0.z;
        o[3] = fmaxf(f23.y, 0.f) * e0.w;
        o[4] = fmaxf(f45.x, 0.f) * e1.x;
        o[5] = fmaxf(f45.y, 0.f) * e1.y;
        o[6] = fmaxf(f67.x, 0.f) * e1.z;
        o[7] = fmaxf(f67.y, 0.f) * e1.w;
        uint4 st;
        st.x = (u32)f2bf(o[0]) | ((u32)f2bf(o[1]) << 16);
        st.y = (u32)f2bf(o[2]) | ((u32)f2bf(o[3]) << 16);
        st.z = (u32)f2bf(o[4]) | ((u32)f2bf(o[5]) << 16);
        st.w = (u32)f2bf(o[6]) | ((u32)f2bf(o[7]) << 16);
        obufT[((size_t)cc * B_BATCH + b) * N_NODES + i] = st;
#pragma unroll
        for (int q = 0; q < 8; q++) {
            sacc[q] += o[q];
            sacc2[q] += o[q] * o[q];
        }
    }

    // ---- stats partials (both halves atomically add to the same slots) ----
#pragma unroll
    for (int q = 0; q < 8; q++) {
        sacc[q] = wave_sum(sacc[q]);
        sacc2[q] = wave_sum(sacc2[q]);
    }
    if (lane == 0) {
#pragma unroll
        for (int q = 0; q < 8; q++) {
            sred[0][wid][q] = sacc[q];
            sred[1][wid][q] = sacc2[q];
        }
    }
    __syncthreads();
    if (t < 16) {
        int q = t & 7, which = t >> 3;
        float v = sred[which][0][q] + sred[which][1][q] + sred[which][2][q] + sred[which][3][q];
        float* dst = which ? stats2 : stats;
        atomicAdd(&dst[(d0 + q) * STATS_STRIDE], v);
    }
}

// ---------------- K5: BN apply + relu + fc — bf16x8 c-panel sweep -----------
__global__ __launch_bounds__(256) void k_out(
    const uint4* __restrict__ obufT, const float* __restrict__ stats,
    const float* __restrict__ stats2, const float* __restrict__ gamma,
    const float* __restrict__ beta, const float* __restrict__ fc_w,
    const float* __restrict__ fc_b, float* __restrict__ out) {
    __shared__ float smean[64], sinv[64], sg[64], sb[64], sf[64];
    int t = threadIdx.x;
    int g = blockIdx.x;                 // 256 = 32 b x 8 n-chunks
    int b = g & 31, nc = g >> 5;
    int n = nc * 256 + t;
    const float invM = 1.0f / (float)BN_TOTAL;

    if (t < 64) {
        float mn = stats[t * STATS_STRIDE] * invM;
        float var = stats2[t * STATS_STRIDE] * invM - mn * mn;
        smean[t] = mn;
        sinv[t] = rsqrtf(var + EPS_BN);
        sg[t] = gamma[t]; sb[t] = beta[t]; sf[t] = fc_w[t];
    }
    __syncthreads();

    float fb = fc_b[0];
    float p = 0.f;
#pragma unroll
    for (int cc = 0; cc < 8; cc++) {
        uint4 hv = obufT[((size_t)cc * B_BATCH + b) * N_NODES + n];
        int d = cc * 8;
        float o[8];
        o[0] = bf2f((u16)(hv.x & 0xFFFFu)); o[1] = bf2f((u16)(hv.x >> 16));
        o[2] = bf2f((u16)(hv.y & 0xFFFFu)); o[3] = bf2f((u16)(hv.y >> 16));
        o[4] = bf2f((u16)(hv.z & 0xFFFFu)); o[5] = bf2f((u16)(hv.z >> 16));
        o[6] = bf2f((u16)(hv.w & 0xFFFFu)); o[7] = bf2f((u16)(hv.w >> 16));
#pragma unroll
        for (int q = 0; q < 8; q++) {
            float v = fmaxf((o[q] - smean[d + q]) * sinv[d + q] * sg[d + q] + sb[d + q], 0.f);
            p = fmaf(v, sf[d + q], p);
        }
    }
    out[b * N_NODES + n] = p + fb;
}

// ---------------- launch ----------------------------------------------------
extern "C" void kernel_launch(void* const* d_in, const int* in_sizes, int n_in,
                              void* d_out, int out_size, void* d_ws, size_t ws_size,
                              hipStream_t stream) {
    const float* x     = (const float*)d_in[0];
    const float* emb   = (const float*)d_in[1];
    const float* W     = (const float*)d_in[2];
    const float* Wb    = (const float*)d_in[3];
    const float* a_src = (const float*)d_in[4];
    const float* a_dst = (const float*)d_in[5];
    const float* gamma = (const float*)d_in[6];
    const float* beta  = (const float*)d_in[7];
    const float* fc_w  = (const float*)d_in[8];
    const float* fc_b  = (const float*)d_in[9];
    float* out = (float*)d_out;

    // Workspace map (re-derived from ELEMENT COUNTS):
    //   stats    [0,        4096)
    //   stats2   [4096,     8192)
    //   idxT     [8192,     180224)   21*2048*4      = 172,032
    //   norms    [180224,   188416)   2048*4         = 8,192
    //   es_embP  [188416,   196608)   2048*4         = 8,192
    //   ed_embP  [196608,   204800)   2048*4         = 8,192
    //   xs2T     [204800,   466944)   65536*4        = 262,144
    //   xd2T     [466944,   729088)   65536*4        = 262,144
    //   paT      [729088,   6234112)  32*21*2048*4   = 5,505,024
    //   dotM     [6234112,  23011328) 2048*2048*4    = 16,777,216
    //   obufT  = dotM alias (8.4 MB bf16x8; dotM dead after k_select)
    char* ws = (char*)d_ws;
    float* stats   = (float*)(ws + 0);
    float* stats2  = (float*)(ws + 4096);
    int*   idxT    = (int*)  (ws + 8192);
    float* norms   = (float*)(ws + 180224);
    float* es_embP = (float*)(ws + 188416);
    float* ed_embP = (float*)(ws + 196608);
    float* xs2T    = (float*)(ws + 204800);
    float* xd2T    = (float*)(ws + 466944);
    u32*   paT     = (u32*)  (ws + 729088);
    float* dotM    = (float*)(ws + 6234112);
    uint4* obufT   = (uint4*)dotM;
    // total: 23,011,328 bytes

    k_preg<<<1104, 256, 0, stream>>>(x, W, Wb, a_src, a_dst, emb,
                                     xs2T, xd2T, es_embP, ed_embP, norms,
                                     dotM, stats, stats2);
    k_select<<<N_NODES / 2, 256, 0, stream>>>(dotM, norms, idxT);
    k_alpha<<<256, 256, 0, stream>>>(idxT, xs2T, xd2T, es_embP, ed_embP, paT);
    k_msg<<<512, 256, 0, stream>>>(x, W, Wb, paT, emb, obufT, stats, stats2);
    k_out<<<256, 256, 0, stream>>>(obufT, stats, stats2, gamma, beta, fc_w, fc_b, out);
}